// Round 2
// baseline (368.754 us; speedup 1.0000x reference)
//
#include <hip/hip_runtime.h>
#include <stdint.h>

// x: (8,16,2000,128) fp32.  Per (b,c,f): causal prefix mean/var over POOL=10
// pooled blocks, normalize.  Single fused pass with decoupled lookback.
#define T_    2000
#define F4_   32        // F/4 float4 per row
#define POOL_ 10
#define BC_   128       // B*C
#define EPS_  1e-5f
#define CPB_  5         // chunks per bc
#define CH_   40        // t1-blocks per chunk (5 iters x 8 groups)
#define L_    5
#define NCHUNK_ 640     // BC_*CPB_

// ws layout: u32[0]=ticket  u32[64..704)=flags  byte 4096+: payload
//   aggS[640][128] aggS2[640][128] incS[640][128] incS2[640][128]

__device__ __forceinline__ void atom_st_f(float* p, float v) {
    __hip_atomic_store((unsigned int*)p, __float_as_uint(v),
                       __ATOMIC_RELAXED, __HIP_MEMORY_SCOPE_AGENT);
}
__device__ __forceinline__ float atom_ld_f(const float* p) {
    return __uint_as_float(__hip_atomic_load((const unsigned int*)p,
                       __ATOMIC_RELAXED, __HIP_MEMORY_SCOPE_AGENT));
}

__global__ __launch_bounds__(256, 2) void fused_cin(
    const float4* __restrict__ x4, float4* __restrict__ out4,
    unsigned int* __restrict__ hdr, float* __restrict__ pay)
{
    __shared__ unsigned int s_vid;
    __shared__ float4 lsS[8][32], lsS2[8][32];
    __shared__ float4 lbS[32], lbS2[32];

    const int tid = threadIdx.x;
    if (tid == 0) s_vid = atomicAdd(hdr, 1u);   // ticket = dispatch order
    __syncthreads();
    const unsigned int vid = s_vid;
    const int bc = vid & (BC_ - 1);   // c-major: chunk c of every bc first
    const int c  = vid >> 7;
    const int g  = tid >> 5;          // t1 subgroup 0..7
    const int l  = tid & 31;          // f4 index

    unsigned int* flags = hdr + 64;
    float* aggS  = pay;
    float* aggS2 = pay + (size_t)NCHUNK_ * 128;
    float* incS  = pay + (size_t)2 * NCHUNK_ * 128;
    float* incS2 = pay + (size_t)3 * NCHUNK_ * 128;

    // ---- Phase A/B: per-t1 sums + intra-chunk inclusive scan ----
    float4 iS[L_], iS2[L_];                       // inclusive within chunk
    float4 aggAcc = {0,0,0,0}, aggAcc2 = {0,0,0,0};
    const int t1_0 = c * CH_;
#pragma unroll
    for (int it = 0; it < L_; ++it) {
        const int t1 = t1_0 + it * 8 + g;
        const float4* p = x4 + (size_t)(bc * T_ + t1 * POOL_) * F4_ + l;
        float4 s = {0,0,0,0}, s2 = {0,0,0,0};
#pragma unroll
        for (int k = 0; k < POOL_; ++k) {
            float4 v = p[k * F4_];
            s.x += v.x; s.y += v.y; s.z += v.z; s.w += v.w;
            s2.x = fmaf(v.x, v.x, s2.x);
            s2.y = fmaf(v.y, v.y, s2.y);
            s2.z = fmaf(v.z, v.z, s2.z);
            s2.w = fmaf(v.w, v.w, s2.w);
        }
        __syncthreads();                 // protect LDS from previous iter reads
        lsS[g][l] = s; lsS2[g][l] = s2;
        __syncthreads();
        float4 run = aggAcc, run2 = aggAcc2;
        float4 mine = run, mine2 = run2;
#pragma unroll
        for (int gg = 0; gg < 8; ++gg) {
            float4 a = lsS[gg][l], a2 = lsS2[gg][l];
            run.x += a.x; run.y += a.y; run.z += a.z; run.w += a.w;
            run2.x += a2.x; run2.y += a2.y; run2.z += a2.z; run2.w += a2.w;
            if (gg == g) { mine = run; mine2 = run2; }
        }
        iS[it] = mine; iS2[it] = mine2;
        aggAcc = run; aggAcc2 = run2;    // batch total carried forward
    }

    // ---- Phase C: publish chunk aggregate (flag=1); last chunk skips ----
    const size_t rec = (size_t)vid * 128 + 4 * l;
    const bool last = (c == CPB_ - 1);
    if (!last && tid < 64) {
        if (tid < 32) {
            atom_st_f(&aggS[rec + 0], aggAcc.x);
            atom_st_f(&aggS[rec + 1], aggAcc.y);
            atom_st_f(&aggS[rec + 2], aggAcc.z);
            atom_st_f(&aggS[rec + 3], aggAcc.w);
        } else {
            atom_st_f(&aggS2[rec + 0], aggAcc2.x);
            atom_st_f(&aggS2[rec + 1], aggAcc2.y);
            atom_st_f(&aggS2[rec + 2], aggAcc2.z);
            atom_st_f(&aggS2[rec + 3], aggAcc2.w);
        }
        if (tid == 0) {
            __threadfence();   // wave-level vmcnt drain covers lanes 0..63
            __hip_atomic_store(&flags[vid], 1u, __ATOMIC_RELEASE,
                               __HIP_MEMORY_SCOPE_AGENT);
        }
    }

    // ---- Phase D: lookback (wave 0); c==0 falls through with carry=0 ----
    if (tid < 64) {
        float4 carry = {0,0,0,0};
        const int half = tid >> 5;               // 0: sum, 1: sum-of-squares
        const float* aggA = half ? aggS2 : aggS;
        const float* incA = half ? incS2 : incS;
        for (int cc = c - 1; cc >= 0; --cc) {
            const unsigned int pv = (unsigned int)(cc * BC_ + bc);
            unsigned int f;
            while ((f = __hip_atomic_load(&flags[pv], __ATOMIC_ACQUIRE,
                                          __HIP_MEMORY_SCOPE_AGENT)) == 0u)
                __builtin_amdgcn_s_sleep(1);
            const size_t r = (size_t)pv * 128 + 4 * l;
            const float* src = (f == 2u) ? incA : aggA;
            carry.x += atom_ld_f(&src[r + 0]);
            carry.y += atom_ld_f(&src[r + 1]);
            carry.z += atom_ld_f(&src[r + 2]);
            carry.w += atom_ld_f(&src[r + 3]);
            if (f == 2u) break;                  // uniform across wave
        }
        if (half == 0) lbS[l] = carry; else lbS2[l] = carry;
        if (!last) {                             // publish inclusive (flag=2)
            float4 inc;
            if (half == 0) {
                inc.x = carry.x + aggAcc.x; inc.y = carry.y + aggAcc.y;
                inc.z = carry.z + aggAcc.z; inc.w = carry.w + aggAcc.w;
                atom_st_f(&incS[rec + 0], inc.x);
                atom_st_f(&incS[rec + 1], inc.y);
                atom_st_f(&incS[rec + 2], inc.z);
                atom_st_f(&incS[rec + 3], inc.w);
            } else {
                inc.x = carry.x + aggAcc2.x; inc.y = carry.y + aggAcc2.y;
                inc.z = carry.z + aggAcc2.z; inc.w = carry.w + aggAcc2.w;
                atom_st_f(&incS2[rec + 0], inc.x);
                atom_st_f(&incS2[rec + 1], inc.y);
                atom_st_f(&incS2[rec + 2], inc.z);
                atom_st_f(&incS2[rec + 3], inc.w);
            }
            if (tid == 0) {
                __threadfence();
                __hip_atomic_store(&flags[vid], 2u, __ATOMIC_RELEASE,
                                   __HIP_MEMORY_SCOPE_AGENT);
            }
        }
    }
    __syncthreads();

    // ---- Phase F: normalize; x re-read is L1/L2/L3-warm ----
    const float4 bS = lbS[l], bS2 = lbS2[l];
#pragma unroll
    for (int it = 0; it < L_; ++it) {
        const int t1 = t1_0 + it * 8 + g;
        const float invn = 1.0f / (float)((t1 + 1) * POOL_);
        float4 m, r;
        m.x = (iS[it].x + bS.x) * invn;
        m.y = (iS[it].y + bS.y) * invn;
        m.z = (iS[it].z + bS.z) * invn;
        m.w = (iS[it].w + bS.w) * invn;
        r.x = rsqrtf(fmaf(-m.x, m.x, (iS2[it].x + bS2.x) * invn) + EPS_);
        r.y = rsqrtf(fmaf(-m.y, m.y, (iS2[it].y + bS2.y) * invn) + EPS_);
        r.z = rsqrtf(fmaf(-m.z, m.z, (iS2[it].z + bS2.z) * invn) + EPS_);
        r.w = rsqrtf(fmaf(-m.w, m.w, (iS2[it].w + bS2.w) * invn) + EPS_);
        const size_t off = (size_t)(bc * T_ + t1 * POOL_) * F4_ + l;
        const float4* p = x4 + off;
        float4* q = out4 + off;
#pragma unroll
        for (int k = 0; k < POOL_; ++k) {
            float4 v = p[k * F4_];
            float4 o;
            o.x = (v.x - m.x) * r.x;
            o.y = (v.y - m.y) * r.y;
            o.z = (v.z - m.z) * r.z;
            o.w = (v.w - m.w) * r.w;
            q[k * F4_] = o;
        }
    }
}

extern "C" void kernel_launch(void* const* d_in, const int* in_sizes, int n_in,
                              void* d_out, int out_size, void* d_ws, size_t ws_size,
                              hipStream_t stream)
{
    const float* x   = (const float*)d_in[0];
    float*       out = (float*)d_out;

    // header (ticket + 640 flags) must be zero each call; payload is
    // flag-guarded so 0xAA poison there is harmless.
    hipMemsetAsync(d_ws, 0, 4096, stream);

    unsigned int* hdr = (unsigned int*)d_ws;
    float*        pay = (float*)((char*)d_ws + 4096);

    fused_cin<<<NCHUNK_, 256, 0, stream>>>(
        (const float4*)x, (float4*)out, hdr, pay);
}